// Round 2
// baseline (304412.964 us; speedup 1.0000x reference)
//
#include <hip/hip_runtime.h>
#include <cstdio>

#define NROWS 8640      // D*T sequential steps
#define HDIM  1024
#define NWG   64        // persistent workgroups
#define RPW   16        // rows per WG = HDIM/NWG
#define LINE_W 32       // floats per 128B line
#define NCHUNK 6        // 16B chunks per WG: [3 data floats | seq]

typedef float vf4 __attribute__((ext_vector_type(4)));

__device__ __forceinline__ float fsig(float x)  { return 1.f / (1.f + __expf(-x)); }
__device__ __forceinline__ float ftanh(float x) { return 2.f / (1.f + __expf(-2.f * x)) - 1.f; }

// LLC-coherent 16B ops (sc0 sc1: bypass non-coherent L1/L2, hit Infinity Cache)
__device__ __forceinline__ vf4 llc_load_f4(const float* p) {
  vf4 v;
  asm volatile("global_load_dwordx4 %0, %1, off sc0 sc1\n\ts_waitcnt vmcnt(0)"
               : "=v"(v) : "v"(p) : "memory");
  return v;
}
__device__ __forceinline__ void llc_store_f4(float* p, vf4 v) {
  asm volatile("global_store_dwordx4 %0, %1, off sc0 sc1" :: "v"(p), "v"(v) : "memory");
}

// Butterfly reduce-scatter: NV per-lane values, summed over 64 lanes.
// On exit v[0] holds the full sum of pair p(lane) (bit-reversed mapping).
template<int NV>
__device__ __forceinline__ void rscatter(float* v, int lane) {
  int nv = NV;
#pragma unroll
  for (int s = 0; s < 6; ++s) {
    int half = nv >> 1;
    if (half >= 1) {
      bool hi = (lane >> s) & 1;
#pragma unroll
      for (int i = 0; i < half; ++i) {
        float pub = hi ? v[i] : v[half + i];
        float rec = __shfl_xor(pub, 1 << s, 64);
        v[i] = (hi ? v[half + i] : v[i]) + rec;
      }
      nv = half;
    } else {
      v[0] += __shfl_xor(v[0], 1 << s, 64);
    }
  }
}

// 64 WGs x 512 threads. WG g owns rows [g*16, g*16+16). Wave w owns columns
// {w*64+lane, 512+w*64+lane}. Weights for all 5 row-slices live in VGPRs.
__global__ __launch_bounds__(512, 2) void scan_kernel(
    const float* __restrict__ pre_ho, const float* __restrict__ pre_i,
    const float* __restrict__ pre_g,  const float* __restrict__ pre_f,
    const float* __restrict__ pre_o,
    const float* __restrict__ w_t,  const float* __restrict__ w_ih,
    const float* __restrict__ w_gh, const float* __restrict__ w_fo,
    const float* __restrict__ w_oh,
    float* __restrict__ lines0, float* __restrict__ lines1,
    float* __restrict__ hs, float* __restrict__ cs)
{
  __shared__ float h_sh[HDIM];
  __shared__ float partial[48 * 9];   // stride 9 breaks bank aliasing

  const int tid  = threadIdx.x;
  const int lane = tid & 63;
  const int w    = tid >> 6;          // wave 0..7
  const int wg   = blockIdx.x;
  const int g16  = wg * RPW;

  for (int i = tid; i < HDIM; i += 512) h_sh[i] = 0.f;

  const int col0 = (w << 6) + lane;   // 0..511
  const int col1 = col0 + 512;

  // Weight slices in registers: wA = [W_t rows | W_oh rows], wB = [W_ih | W_gh | W_fo]
  float wA[32][2], wB[48][2];
#pragma unroll
  for (int p = 0; p < 16; ++p) {
    wA[p][0]    = w_t [(g16+p)*HDIM + col0];  wA[p][1]    = w_t [(g16+p)*HDIM + col1];
    wA[16+p][0] = w_oh[(g16+p)*HDIM + col0];  wA[16+p][1] = w_oh[(g16+p)*HDIM + col1];
    wB[p][0]    = w_ih[(g16+p)*HDIM + col0];  wB[p][1]    = w_ih[(g16+p)*HDIM + col1];
    wB[16+p][0] = w_gh[(g16+p)*HDIM + col0];  wB[16+p][1] = w_gh[(g16+p)*HDIM + col1];
    wB[32+p][0] = w_fo[(g16+p)*HDIM + col0];  wB[32+p][1] = w_fo[(g16+p)*HDIM + col1];
  }

  const int l5 = lane & 31;
  const int p32 = ((l5&1)<<4)|((l5&2)<<2)|(l5&4)|((l5&8)>>2)|((l5&16)>>4);
  const int l4 = lane & 15;
  const int p16 = ((l4&1)<<3)|((l4&2)<<1)|((l4&4)>>1)|((l4&8)>>3);

  // wave-0 lanes 0..15 hold per-row persistent state
  float cprev = 0.f, oo = 0.f;
  float ph = 0.f, po = 0.f, pi = 0.f, pg = 0.f, pf = 0.f;
  if (w == 0 && lane < 16) {
    ph = pre_ho[g16+lane]; po = pre_o[g16+lane];
    pi = pre_i[g16+lane];  pg = pre_g[g16+lane]; pf = pre_f[g16+lane];
  }

  const int gp  = tid / NCHUNK;       // polled WG (tid < 384)
  const int cp  = tid % NCHUNK;       // polled chunk
  const int c3  = cp * 3;
  const long ofs = (long)gp * LINE_W + cp * 4;

  __syncthreads();

  for (int n = 0; n < NROWS; ++n) {
    // ======== phase A: h_o = sig(ph + 2*W_t h), o = sig(po + W_oh h) ========
    float h0 = h_sh[col0], h1 = h_sh[col1];
    {
      float v[32];
#pragma unroll
      for (int p = 0; p < 32; ++p) v[p] = wA[p][0]*h0 + wA[p][1]*h1;
      rscatter<32>(v, lane);
      if (lane < 32) partial[p32*9 + w] = v[0];
    }
    __syncthreads();
    const int tgtA = 2*n + 1;
    if (w == 0) {
      float s = 0.f;
      if (lane < 32) {
#pragma unroll
        for (int k = 0; k < 8; ++k) s += partial[lane*9 + k];
      }
      float uo_s = __shfl(s, 16 + lane, 64);
      float res = 0.f;
      if (lane < 16) {
        res = fsig(ph + 2.f * s);
        oo  = fsig(po + uo_s);
      }
      float cx = __shfl(res, lane*3,     64);
      float cy = __shfl(res, lane*3 + 1, 64);
      float cz = __shfl(res, lane*3 + 2, 64);
      if (lane < NCHUNK) {
        vf4 d; d.x = cx; d.y = cy; d.z = cz; d.w = __int_as_float(tgtA);
        llc_store_f4(lines0 + wg*LINE_W + lane*4, d);
      }
    }
    if (tid < NWG*NCHUNK) {
      const float* ca = lines0 + ofs;
      vf4 d = {0.f,0.f,0.f,0.f}; bool ok = false;
      do {
        vf4 t2 = llc_load_f4(ca);
        if (!ok && __float_as_int(t2.w) >= tgtA) { d = t2; ok = true; }
      } while (!__all(ok));
      int b = gp*RPW + c3;
      h_sh[b] = d.x;
      if (c3 + 1 < RPW) h_sh[b+1] = d.y;
      if (c3 + 2 < RPW) h_sh[b+2] = d.z;
    }
    __syncthreads();

    // ======== phase B: gates from h_o; c,h update ========
    float g0 = h_sh[col0], g1 = h_sh[col1];
    {
      float v[32];
#pragma unroll
      for (int p = 0; p < 32; ++p) v[p] = wB[p][0]*g0 + wB[p][1]*g1;
      rscatter<32>(v, lane);
      if (lane < 32) partial[p32*9 + w] = v[0];
    }
    {
      float u[16];
#pragma unroll
      for (int q = 0; q < 16; ++q) u[q] = wB[32+q][0]*g0 + wB[32+q][1]*g1;
      rscatter<16>(u, lane);
      if (lane < 16) partial[(32+p16)*9 + w] = u[0];
    }
    __syncthreads();
    const int tgtB = 2*n + 2;
    if (w == 0) {
      float s = 0.f;
      if (lane < 48) {
#pragma unroll
        for (int k = 0; k < 8; ++k) s += partial[lane*9 + k];
      }
      float ug_s = __shfl(s, 16 + lane, 64);
      float uf_s = __shfl(s, 32 + lane, 64);
      float hh = 0.f;
      if (lane < 16) {
        float ii = fsig(pi + s);
        float gg = ftanh(pg + ug_s);
        float ff = fsig(pf + uf_s);
        float cc = ff * cprev + ii * gg;
        hh = oo * ftanh(cc);
        cprev = cc;
        hs[(long)n*HDIM + g16 + lane] = hh;
        cs[(long)n*HDIM + g16 + lane] = cc;
        if (n + 1 < NROWS) {   // prefetch next step's pre_* during store/poll
          long o2 = (long)(n+1)*HDIM + g16 + lane;
          ph = pre_ho[o2]; po = pre_o[o2];
          pi = pre_i[o2];  pg = pre_g[o2]; pf = pre_f[o2];
        }
      }
      float cx = __shfl(hh, lane*3,     64);
      float cy = __shfl(hh, lane*3 + 1, 64);
      float cz = __shfl(hh, lane*3 + 2, 64);
      if (lane < NCHUNK) {
        vf4 d; d.x = cx; d.y = cy; d.z = cz; d.w = __int_as_float(tgtB);
        llc_store_f4(lines1 + wg*LINE_W + lane*4, d);
      }
    }
    if (tid < NWG*NCHUNK) {
      const float* ca = lines1 + ofs;
      vf4 d = {0.f,0.f,0.f,0.f}; bool ok = false;
      do {
        vf4 t2 = llc_load_f4(ca);
        if (!ok && __float_as_int(t2.w) >= tgtB) { d = t2; ok = true; }
      } while (!__all(ok));
      int b = gp*RPW + c3;
      h_sh[b] = d.x;
      if (c3 + 1 < RPW) h_sh[b+1] = d.y;
      if (c3 + 2 < RPW) h_sh[b+2] = d.z;
    }
    __syncthreads();
  }
}

// ---------- generic accumulating GEMM: C[n,h] += sum_k A[rowmap(n),k]*B[h,k] ----------
__global__ __launch_bounds__(256) void gemm_acc(
    float* __restrict__ C, const float* __restrict__ A, const float* __restrict__ B,
    int K, int shift, int minn)
{
  __shared__ float Asf[16 * 68];
  __shared__ float Bsf[16 * 68];
  const int tid = threadIdx.x;
  const int h0  = blockIdx.x * 64;
  const int n0  = blockIdx.y * 64;
  const int r   = tid >> 2;
  const int kq  = (tid & 3) << 2;
  const int tx  = tid & 15, ty = tid >> 4;

  int arow = n0 + r;
  int src  = arow - shift; if (src < 0) src += NROWS;
  const bool avalid = (arow >= minn);
  const float* Ap = A + (long)src * K + kq;
  const float* Bp = B + (long)(h0 + r) * K + kq;

  vf4 acc0 = {0.f,0.f,0.f,0.f}, acc1 = {0.f,0.f,0.f,0.f};
  vf4 acc2 = {0.f,0.f,0.f,0.f}, acc3 = {0.f,0.f,0.f,0.f};
  const vf4 zero = {0.f,0.f,0.f,0.f};

  for (int k0 = 0; k0 < K; k0 += 16) {
    vf4 av = avalid ? *(const vf4*)(Ap + k0) : zero;
    vf4 bv = *(const vf4*)(Bp + k0);
    __syncthreads();
    Asf[(kq+0)*68 + r] = av.x;  Asf[(kq+1)*68 + r] = av.y;
    Asf[(kq+2)*68 + r] = av.z;  Asf[(kq+3)*68 + r] = av.w;
    Bsf[(kq+0)*68 + r] = bv.x;  Bsf[(kq+1)*68 + r] = bv.y;
    Bsf[(kq+2)*68 + r] = bv.z;  Bsf[(kq+3)*68 + r] = bv.w;
    __syncthreads();
#pragma unroll
    for (int c = 0; c < 16; ++c) {
      vf4 a = *(const vf4*)(Asf + c*68 + (ty << 2));
      vf4 b = *(const vf4*)(Bsf + c*68 + (tx << 2));
      acc0 += a.x * b;
      acc1 += a.y * b;
      acc2 += a.z * b;
      acc3 += a.w * b;
    }
  }
  float* cp = C + (long)(n0 + (ty << 2)) * HDIM + h0 + (tx << 2);
  { vf4 t = *(vf4*)(cp + 0*HDIM); t += acc0; *(vf4*)(cp + 0*HDIM) = t; }
  { vf4 t = *(vf4*)(cp + 1*HDIM); t += acc1; *(vf4*)(cp + 1*HDIM) = t; }
  { vf4 t = *(vf4*)(cp + 2*HDIM); t += acc2; *(vf4*)(cp + 2*HDIM) = t; }
  { vf4 t = *(vf4*)(cp + 3*HDIM); t += acc3; *(vf4*)(cp + 3*HDIM) = t; }
}

__global__ void bias_init(float* __restrict__ out, const float* __restrict__ bias) {
  int i = blockIdx.x * blockDim.x + threadIdx.x;
  vf4 v = {0.f,0.f,0.f,0.f};
  if (bias) { int h = (i << 2) & (HDIM - 1); v = *(const vf4*)(bias + h); }
  *((vf4*)out + i) = v;
}

__global__ void sigmoid_k(float* __restrict__ e) {
  int i = blockIdx.x * blockDim.x + threadIdx.x;
  vf4 v = *((vf4*)e + i);
  v.x = fsig(v.x); v.y = fsig(v.y); v.z = fsig(v.z); v.w = fsig(v.w);
  *((vf4*)e + i) = v;
}

extern "C" void kernel_launch(void* const* d_in, const int* in_sizes, int n_in,
                              void* d_out, int out_size, void* d_ws, size_t ws_size,
                              hipStream_t stream) {
  const float* x    = (const float*)d_in[0];
  const float* xw   = (const float*)d_in[1];
  const float* w_ix = (const float*)d_in[2];
  const float* w_ih = (const float*)d_in[3];
  const float* w_ie = (const float*)d_in[4];
  const float* b_i  = (const float*)d_in[5];
  const float* w_fx = (const float*)d_in[6];
  const float* w_fo = (const float*)d_in[7];
  const float* w_fe = (const float*)d_in[8];
  const float* b_f  = (const float*)d_in[9];
  const float* w_ox = (const float*)d_in[10];
  const float* w_oh = (const float*)d_in[11];
  const float* w_oe = (const float*)d_in[12];
  const float* b_o  = (const float*)d_in[13];
  const float* w_gx = (const float*)d_in[14];
  const float* w_gh = (const float*)d_in[15];
  const float* b_g  = (const float*)d_in[16];
  const float* w_d  = (const float*)d_in[17];
  const float* w_w  = (const float*)d_in[18];
  const float* w_m  = (const float*)d_in[19];
  const float* w_t  = (const float*)d_in[20];
  const float* w_e  = (const float*)d_in[21];
  const float* b_e  = (const float*)d_in[22];

  const long S = (long)NROWS * HDIM;
  float* ws_f   = (float*)d_ws;
  float* pre_ho = ws_f + 0*S;
  float* pre_i  = ws_f + 1*S;
  float* pre_g  = ws_f + 2*S;
  float* pre_f  = ws_f + 3*S;
  float* pre_o  = ws_f + 4*S;
  float* e_buf  = ws_f + 5*S;
  float* lines0 = ws_f + 6*S;
  float* lines1 = lines0 + NWG*LINE_W;

  size_t need = (size_t)(6*S + 2*NWG*LINE_W) * sizeof(float);
  if (ws_size < need) {
    fprintf(stderr, "kernel_launch: ws too small (have %zu, need %zu)\n", ws_size, need);
    return;
  }

  dim3 ggrid(HDIM/64, NROWS/64);

  bias_init<<<NROWS, 256, 0, stream>>>(pre_i, b_i);
  bias_init<<<NROWS, 256, 0, stream>>>(pre_g, b_g);
  bias_init<<<NROWS, 256, 0, stream>>>(pre_f, b_f);
  bias_init<<<NROWS, 256, 0, stream>>>(pre_o, b_o);
  bias_init<<<NROWS, 256, 0, stream>>>(e_buf, b_e);
  bias_init<<<NROWS, 256, 0, stream>>>(pre_ho, nullptr);

  gemm_acc<<<ggrid, 256, 0, stream>>>(e_buf, xw, w_e, 64, 0, 0);
  sigmoid_k<<<NROWS, 256, 0, stream>>>(e_buf);

  gemm_acc<<<ggrid, 256, 0, stream>>>(pre_i, x, w_ix, 512, 0, 0);
  gemm_acc<<<ggrid, 256, 0, stream>>>(pre_g, x, w_gx, 512, 0, 0);
  gemm_acc<<<ggrid, 256, 0, stream>>>(pre_f, x, w_fx, 512, 0, 0);
  gemm_acc<<<ggrid, 256, 0, stream>>>(pre_o, x, w_ox, 512, 0, 0);
  gemm_acc<<<ggrid, 256, 0, stream>>>(pre_i, e_buf, w_ie, 1024, 0, 0);
  gemm_acc<<<ggrid, 256, 0, stream>>>(pre_f, e_buf, w_fe, 1024, 0, 0);
  gemm_acc<<<ggrid, 256, 0, stream>>>(pre_o, e_buf, w_oe, 1024, 0, 0);
  gemm_acc<<<ggrid, 256, 0, stream>>>(pre_ho, x, w_d, 512,   96,   96);
  gemm_acc<<<ggrid, 256, 0, stream>>>(pre_ho, x, w_w, 512,  576,  672);
  gemm_acc<<<ggrid, 256, 0, stream>>>(pre_ho, x, w_m, 512, 2784, 2688);

  hipMemsetAsync(lines0, 0, 2 * NWG * LINE_W * sizeof(float), stream);

  float* hs = (float*)d_out;
  float* cs = hs + S;
  scan_kernel<<<NWG, 512, 0, stream>>>(pre_ho, pre_i, pre_g, pre_f, pre_o,
                                       w_t, w_ih, w_gh, w_fo, w_oh,
                                       lines0, lines1, hs, cs);
}

// Round 3
// 46662.561 us; speedup vs baseline: 6.5237x; 6.5237x over previous
//
#include <hip/hip_runtime.h>
#include <cstdio>

#define NROWS 8640      // D*T sequential steps
#define HDIM  1024
#define NWG   64        // persistent workgroups (1 per CU, 64 << 256 CUs -> co-resident)
#define RPW   16        // rows per WG
#define LINE_W 32       // floats per WG per publish buffer (128B line: 8 chunks x 16B)

typedef float vf4 __attribute__((ext_vector_type(4)));

__device__ __forceinline__ float fsig(float x)  { return 1.f / (1.f + __expf(-x)); }
__device__ __forceinline__ float ftanh(float x) { return 2.f / (1.f + __expf(-2.f * x)) - 1.f; }

// LLC-coherent 16B ops (sc0 sc1: bypass non-coherent per-XCD L1/L2, hit Infinity Cache)
__device__ __forceinline__ vf4 llc_load_f4(const float* p) {
  vf4 v;
  asm volatile("global_load_dwordx4 %0, %1, off sc0 sc1\n\ts_waitcnt vmcnt(0)"
               : "=v"(v) : "v"(p) : "memory");
  return v;
}
__device__ __forceinline__ void llc_store_f4(float* p, vf4 v) {
  asm volatile("global_store_dwordx4 %0, %1, off sc0 sc1" :: "v"(p), "v"(v) : "memory");
}

__device__ __forceinline__ float dot4(vf4 a, vf4 b) {
  return a.x*b.x + a.y*b.y + a.z*b.z + a.w*b.w;
}

// full-wave butterfly sum (xor-only: measured 0 bank conflicts in round 1)
#define WRED(x) { x += __shfl_xor(x,32,64); x += __shfl_xor(x,16,64); \
                  x += __shfl_xor(x, 8,64); x += __shfl_xor(x, 4,64); \
                  x += __shfl_xor(x, 2,64); x += __shfl_xor(x, 1,64); }

// 64 WGs x 512 threads (8 waves). WG g owns rows [16g,16g+16); wave w owns rows
// 16g+2w, 16g+2w+1 of all 5 matrices, weights in VGPRs (lane l covers h-columns
// {4l..4l+3} + 256m, m=0..3). Per phase each wave publishes its 2 results as one
// 16B chunk [v0 v1 seq pad]; every thread polls exactly one (srcWG,srcWave) chunk
// and scatters 2 floats into LDS h_sh. Seq-in-chunk => one LLC RTT per phase.
__global__ __launch_bounds__(512, 2) void scan_kernel(
    const float* __restrict__ pre_ho, const float* __restrict__ pre_i,
    const float* __restrict__ pre_g,  const float* __restrict__ pre_f,
    const float* __restrict__ pre_o,
    const float* __restrict__ w_t,  const float* __restrict__ w_ih,
    const float* __restrict__ w_gh, const float* __restrict__ w_fo,
    const float* __restrict__ w_oh,
    float* __restrict__ lines0, float* __restrict__ lines1,
    float* __restrict__ hs, float* __restrict__ cs)
{
  __shared__ float h_sh[HDIM];

  const int tid  = threadIdx.x;
  const int lane = tid & 63;
  const int w    = tid >> 6;          // wave 0..7
  const int wg   = blockIdx.x;
  const int r0   = wg * RPW + 2 * w;  // this wave's first row
  const int myrow = r0 + lane;        // valid for lane<2

  for (int i = tid; i < HDIM; i += 512) h_sh[i] = 0.f;

  // weight fragments: Wf[mat][row][m]; mat: 0=w_t 1=w_oh 2=w_ih 3=w_gh 4=w_fo
  vf4 Wf[5][2][4];
  {
    const float* Wp[5] = { w_t, w_oh, w_ih, w_gh, w_fo };
#pragma unroll
    for (int mt = 0; mt < 5; ++mt)
#pragma unroll
      for (int rr = 0; rr < 2; ++rr)
#pragma unroll
        for (int m = 0; m < 4; ++m)
          Wf[mt][rr][m] = *(const vf4*)(Wp[mt] + (long)(r0+rr)*HDIM + m*256 + 4*lane);
  }

  // per-row state in lanes 0,1 of the owning wave
  float cprev = 0.f, oo = 0.f;
  float ph = 0.f, po = 0.f, pi = 0.f, pg = 0.f, pf = 0.f;
  if (lane < 2) {
    ph = pre_ho[myrow]; po = pre_o[myrow];
    pi = pre_i[myrow];  pg = pre_g[myrow]; pf = pre_f[myrow];
  }

  // poll assignment: thread t polls chunk (srcWG = t>>3, srcWave = t&7)
  const long pofs = (long)(tid >> 3) * LINE_W + (long)(tid & 7) * 4;
  const int  dsh  = 2 * tid;          // h_sh scatter base = srcWG*16 + srcWave*2
  const float* pollA = lines0 + pofs;
  const float* pollB = lines1 + pofs;
  float* pubA = lines0 + (long)wg * LINE_W + (long)w * 4;
  float* pubB = lines1 + (long)wg * LINE_W + (long)w * 4;

  __syncthreads();

  for (int n = 0; n < NROWS; ++n) {
    const int tgtA = 2*n + 1, tgtB = 2*n + 2;

    // ======== phase A: h_o = sig(ph + 2*W_t h_prev), o = sig(po + W_oh h_prev) ====
    {
      vf4 h0 = *(const vf4*)(h_sh + 4*lane);
      vf4 h1 = *(const vf4*)(h_sh + 4*lane + 256);
      vf4 h2 = *(const vf4*)(h_sh + 4*lane + 512);
      vf4 h3 = *(const vf4*)(h_sh + 4*lane + 768);
      float t0 = dot4(Wf[0][0][0],h0)+dot4(Wf[0][0][1],h1)+dot4(Wf[0][0][2],h2)+dot4(Wf[0][0][3],h3);
      float t1 = dot4(Wf[0][1][0],h0)+dot4(Wf[0][1][1],h1)+dot4(Wf[0][1][2],h2)+dot4(Wf[0][1][3],h3);
      float o0 = dot4(Wf[1][0][0],h0)+dot4(Wf[1][0][1],h1)+dot4(Wf[1][0][2],h2)+dot4(Wf[1][0][3],h3);
      float o1 = dot4(Wf[1][1][0],h0)+dot4(Wf[1][1][1],h1)+dot4(Wf[1][1][2],h2)+dot4(Wf[1][1][3],h3);
      WRED(t0); WRED(t1); WRED(o0); WRED(o1);
      float hov = 0.f;
      if (lane < 2) {
        float ut = lane ? t1 : t0;
        float uo = lane ? o1 : o0;
        hov = fsig(ph + 2.f * ut);
        oo  = fsig(po + uo);
      }
      float hon = __shfl_xor(hov, 1, 64);   // lane0 gets lane1's value
      if (lane == 0) {
        vf4 d; d.x = hov; d.y = hon; d.z = __int_as_float(tgtA); d.w = 0.f;
        llc_store_f4(pubA, d);
      }
    }
    __syncthreads();                         // all h_prev reads retired
    {
      vf4 d;
      do { d = llc_load_f4(pollA); } while (__float_as_int(d.z) < tgtA);
      *(float2*)(h_sh + dsh) = make_float2(d.x, d.y);
    }
    __syncthreads();                         // h_sh now holds h_o

    // ======== phase B: gates from h_o; c,h update ========
    {
      // prefetch next step's pre_* early (overlaps dot compute)
      float ph2 = 0.f, po2 = 0.f, pi2 = 0.f, pg2 = 0.f, pf2 = 0.f;
      if (lane < 2 && n + 1 < NROWS) {
        long o2 = (long)(n+1)*HDIM + myrow;
        ph2 = pre_ho[o2]; po2 = pre_o[o2];
        pi2 = pre_i[o2];  pg2 = pre_g[o2]; pf2 = pre_f[o2];
      }
      vf4 h0 = *(const vf4*)(h_sh + 4*lane);
      vf4 h1 = *(const vf4*)(h_sh + 4*lane + 256);
      vf4 h2 = *(const vf4*)(h_sh + 4*lane + 512);
      vf4 h3 = *(const vf4*)(h_sh + 4*lane + 768);
      float i0 = dot4(Wf[2][0][0],h0)+dot4(Wf[2][0][1],h1)+dot4(Wf[2][0][2],h2)+dot4(Wf[2][0][3],h3);
      float i1 = dot4(Wf[2][1][0],h0)+dot4(Wf[2][1][1],h1)+dot4(Wf[2][1][2],h2)+dot4(Wf[2][1][3],h3);
      float g0 = dot4(Wf[3][0][0],h0)+dot4(Wf[3][0][1],h1)+dot4(Wf[3][0][2],h2)+dot4(Wf[3][0][3],h3);
      float g1 = dot4(Wf[3][1][0],h0)+dot4(Wf[3][1][1],h1)+dot4(Wf[3][1][2],h2)+dot4(Wf[3][1][3],h3);
      float f0 = dot4(Wf[4][0][0],h0)+dot4(Wf[4][0][1],h1)+dot4(Wf[4][0][2],h2)+dot4(Wf[4][0][3],h3);
      float f1 = dot4(Wf[4][1][0],h0)+dot4(Wf[4][1][1],h1)+dot4(Wf[4][1][2],h2)+dot4(Wf[4][1][3],h3);
      WRED(i0); WRED(i1); WRED(g0); WRED(g1); WRED(f0); WRED(f1);
      float hhv = 0.f;
      if (lane < 2) {
        float ui = lane ? i1 : i0;
        float ug = lane ? g1 : g0;
        float uf = lane ? f1 : f0;
        float ii = fsig(pi + ui);
        float gg = ftanh(pg + ug);
        float ff = fsig(pf + uf);
        float cc = ff * cprev + ii * gg;
        hhv = oo * ftanh(cc);
        cprev = cc;
        hs[(long)n*HDIM + myrow] = hhv;
        cs[(long)n*HDIM + myrow] = cc;
      }
      float hhn = __shfl_xor(hhv, 1, 64);
      if (lane == 0) {
        vf4 d; d.x = hhv; d.y = hhn; d.z = __int_as_float(tgtB); d.w = 0.f;
        llc_store_f4(pubB, d);
      }
      ph = ph2; po = po2; pi = pi2; pg = pg2; pf = pf2;
    }
    __syncthreads();                         // all h_o reads retired
    {
      vf4 d;
      do { d = llc_load_f4(pollB); } while (__float_as_int(d.z) < tgtB);
      *(float2*)(h_sh + dsh) = make_float2(d.x, d.y);
    }
    __syncthreads();                         // h_sh now holds new h
  }
}

// ---------- generic accumulating GEMM: C[n,h] += sum_k A[rowmap(n),k]*B[h,k] ----------
__global__ __launch_bounds__(256) void gemm_acc(
    float* __restrict__ C, const float* __restrict__ A, const float* __restrict__ B,
    int K, int shift, int minn)
{
  __shared__ float Asf[16 * 68];
  __shared__ float Bsf[16 * 68];
  const int tid = threadIdx.x;
  const int h0  = blockIdx.x * 64;
  const int n0  = blockIdx.y * 64;
  const int r   = tid >> 2;
  const int kq  = (tid & 3) << 2;
  const int tx  = tid & 15, ty = tid >> 4;

  int arow = n0 + r;
  int src  = arow - shift; if (src < 0) src += NROWS;
  const bool avalid = (arow >= minn);
  const float* Ap = A + (long)src * K + kq;
  const float* Bp = B + (long)(h0 + r) * K + kq;

  vf4 acc0 = {0.f,0.f,0.f,0.f}, acc1 = {0.f,0.f,0.f,0.f};
  vf4 acc2 = {0.f,0.f,0.f,0.f}, acc3 = {0.f,0.f,0.f,0.f};
  const vf4 zero = {0.f,0.f,0.f,0.f};

  for (int k0 = 0; k0 < K; k0 += 16) {
    vf4 av = avalid ? *(const vf4*)(Ap + k0) : zero;
    vf4 bv = *(const vf4*)(Bp + k0);
    __syncthreads();
    Asf[(kq+0)*68 + r] = av.x;  Asf[(kq+1)*68 + r] = av.y;
    Asf[(kq+2)*68 + r] = av.z;  Asf[(kq+3)*68 + r] = av.w;
    Bsf[(kq+0)*68 + r] = bv.x;  Bsf[(kq+1)*68 + r] = bv.y;
    Bsf[(kq+2)*68 + r] = bv.z;  Bsf[(kq+3)*68 + r] = bv.w;
    __syncthreads();
#pragma unroll
    for (int c = 0; c < 16; ++c) {
      vf4 a = *(const vf4*)(Asf + c*68 + (ty << 2));
      vf4 b = *(const vf4*)(Bsf + c*68 + (tx << 2));
      acc0 += a.x * b;
      acc1 += a.y * b;
      acc2 += a.z * b;
      acc3 += a.w * b;
    }
  }
  float* cp = C + (long)(n0 + (ty << 2)) * HDIM + h0 + (tx << 2);
  { vf4 t = *(vf4*)(cp + 0*HDIM); t += acc0; *(vf4*)(cp + 0*HDIM) = t; }
  { vf4 t = *(vf4*)(cp + 1*HDIM); t += acc1; *(vf4*)(cp + 1*HDIM) = t; }
  { vf4 t = *(vf4*)(cp + 2*HDIM); t += acc2; *(vf4*)(cp + 2*HDIM) = t; }
  { vf4 t = *(vf4*)(cp + 3*HDIM); t += acc3; *(vf4*)(cp + 3*HDIM) = t; }
}

__global__ void bias_init(float* __restrict__ out, const float* __restrict__ bias) {
  int i = blockIdx.x * blockDim.x + threadIdx.x;
  vf4 v = {0.f,0.f,0.f,0.f};
  if (bias) { int h = (i << 2) & (HDIM - 1); v = *(const vf4*)(bias + h); }
  *((vf4*)out + i) = v;
}

__global__ void sigmoid_k(float* __restrict__ e) {
  int i = blockIdx.x * blockDim.x + threadIdx.x;
  vf4 v = *((vf4*)e + i);
  v.x = fsig(v.x); v.y = fsig(v.y); v.z = fsig(v.z); v.w = fsig(v.w);
  *((vf4*)e + i) = v;
}

extern "C" void kernel_launch(void* const* d_in, const int* in_sizes, int n_in,
                              void* d_out, int out_size, void* d_ws, size_t ws_size,
                              hipStream_t stream) {
  const float* x    = (const float*)d_in[0];
  const float* xw   = (const float*)d_in[1];
  const float* w_ix = (const float*)d_in[2];
  const float* w_ih = (const float*)d_in[3];
  const float* w_ie = (const float*)d_in[4];
  const float* b_i  = (const float*)d_in[5];
  const float* w_fx = (const float*)d_in[6];
  const float* w_fo = (const float*)d_in[7];
  const float* w_fe = (const float*)d_in[8];
  const float* b_f  = (const float*)d_in[9];
  const float* w_ox = (const float*)d_in[10];
  const float* w_oh = (const float*)d_in[11];
  const float* w_oe = (const float*)d_in[12];
  const float* b_o  = (const float*)d_in[13];
  const float* w_gx = (const float*)d_in[14];
  const float* w_gh = (const float*)d_in[15];
  const float* b_g  = (const float*)d_in[16];
  const float* w_d  = (const float*)d_in[17];
  const float* w_w  = (const float*)d_in[18];
  const float* w_m  = (const float*)d_in[19];
  const float* w_t  = (const float*)d_in[20];
  const float* w_e  = (const float*)d_in[21];
  const float* b_e  = (const float*)d_in[22];

  const long S = (long)NROWS * HDIM;
  float* ws_f   = (float*)d_ws;
  float* pre_ho = ws_f + 0*S;
  float* pre_i  = ws_f + 1*S;
  float* pre_g  = ws_f + 2*S;
  float* pre_f  = ws_f + 3*S;
  float* pre_o  = ws_f + 4*S;
  float* e_buf  = ws_f + 5*S;
  float* lines0 = ws_f + 6*S;
  float* lines1 = lines0 + NWG*LINE_W;

  size_t need = (size_t)(6*S + 2*NWG*LINE_W) * sizeof(float);
  if (ws_size < need) {
    fprintf(stderr, "kernel_launch: ws too small (have %zu, need %zu)\n", ws_size, need);
    return;
  }

  dim3 ggrid(HDIM/64, NROWS/64);

  bias_init<<<NROWS, 256, 0, stream>>>(pre_i, b_i);
  bias_init<<<NROWS, 256, 0, stream>>>(pre_g, b_g);
  bias_init<<<NROWS, 256, 0, stream>>>(pre_f, b_f);
  bias_init<<<NROWS, 256, 0, stream>>>(pre_o, b_o);
  bias_init<<<NROWS, 256, 0, stream>>>(e_buf, b_e);
  bias_init<<<NROWS, 256, 0, stream>>>(pre_ho, nullptr);

  gemm_acc<<<ggrid, 256, 0, stream>>>(e_buf, xw, w_e, 64, 0, 0);
  sigmoid_k<<<NROWS, 256, 0, stream>>>(e_buf);

  gemm_acc<<<ggrid, 256, 0, stream>>>(pre_i, x, w_ix, 512, 0, 0);
  gemm_acc<<<ggrid, 256, 0, stream>>>(pre_g, x, w_gx, 512, 0, 0);
  gemm_acc<<<ggrid, 256, 0, stream>>>(pre_f, x, w_fx, 512, 0, 0);
  gemm_acc<<<ggrid, 256, 0, stream>>>(pre_o, x, w_ox, 512, 0, 0);
  gemm_acc<<<ggrid, 256, 0, stream>>>(pre_i, e_buf, w_ie, 1024, 0, 0);
  gemm_acc<<<ggrid, 256, 0, stream>>>(pre_f, e_buf, w_fe, 1024, 0, 0);
  gemm_acc<<<ggrid, 256, 0, stream>>>(pre_o, e_buf, w_oe, 1024, 0, 0);
  gemm_acc<<<ggrid, 256, 0, stream>>>(pre_ho, x, w_d, 512,   96,   96);
  gemm_acc<<<ggrid, 256, 0, stream>>>(pre_ho, x, w_w, 512,  576,  672);
  gemm_acc<<<ggrid, 256, 0, stream>>>(pre_ho, x, w_m, 512, 2784, 2688);

  hipMemsetAsync(lines0, 0, 2 * NWG * LINE_W * sizeof(float), stream);

  float* hs = (float*)d_out;
  float* cs = hs + S;
  scan_kernel<<<NWG, 512, 0, stream>>>(pre_ho, pre_i, pre_g, pre_f, pre_o,
                                       w_t, w_ih, w_gh, w_fo, w_oh,
                                       lines0, lines1, hs, cs);
}